// Round 7
// baseline (142.798 us; speedup 1.0000x reference)
//
#include <hip/hip_runtime.h>

// Problem constants (B=4, C=64, H=W=128, O=64, K=3, stride=1, pad=1, dil=1)
#define B_   4
#define C_   64
#define O_   64
#define H_   128
#define W_   128
#define HW_  (H_ * W_)
#define KK_  9
#define M_   18          // 2*KK offset channels
#define GHW  (HW_ * 4)   // shorts per 4-channel G-plane of xT

typedef short  short8  __attribute__((ext_vector_type(8)));
typedef float  floatx4 __attribute__((ext_vector_type(4)));
typedef unsigned short ushort4v __attribute__((ext_vector_type(4)));
typedef unsigned short ushort8v __attribute__((ext_vector_type(8)));

static __device__ __forceinline__ unsigned short f2bf(float f) {
    unsigned int u = __float_as_uint(f);
    u += 0x7FFFu + ((u >> 16) & 1u);     // round-to-nearest-even
    return (unsigned short)(u >> 16);
}
static __device__ __forceinline__ float bf2f(unsigned short s) {
    return __uint_as_float((unsigned int)s << 16);
}

// ---------------------------------------------------------------------------
// Prep (single launch): blocks [0,512) transpose x into c4-interleaved bf16
// xT[b][G][y][x][c4] (G = c>>2); blocks [512,656) repack both weight tensors:
//   wtb [o][tap*64+c]  -- main-conv B-frag layout
//   owtb[tap][m32][c]  -- offset-conv B-frag layout (m padded to 32)
// c4 layout => an x-corner pair (x0, x0+1) x 4 channels is ONE 16 B load.
// ---------------------------------------------------------------------------
__global__ __launch_bounds__(256) void prep(
        const float* __restrict__ x, const float* __restrict__ w,
        const float* __restrict__ ow, unsigned short* __restrict__ xT,
        unsigned short* __restrict__ wtb, unsigned short* __restrict__ owtb) {
    const int blk = blockIdx.x;
    if (blk < 512) {
        __shared__ unsigned short T[128][72];   // [x][c], row padded to 72
        const int tid = threadIdx.x;
        const int y = blk & (H_ - 1);
        const int b = blk >> 7;
        const float* xby = x + (size_t)b * C_ * HW_ + y * W_;
        for (int i = tid; i < C_ * W_; i += 256) {
            const int c = i >> 7, xc = i & 127;
            T[xc][c] = f2bf(xby[(size_t)c * HW_ + xc]);
        }
        __syncthreads();
        unsigned short* dst = xT + (size_t)b * 16 * GHW + y * (W_ * 4);
        for (int j = tid; j < 2048; j += 256) {
            const int G  = j >> 7;          // 16 channel-groups of 4
            const int x8 = j & 127;         // lanes consecutive x -> coalesced
            const ushort4v pk = *(const ushort4v*)&T[x8][G * 4];
            *(ushort4v*)&dst[(size_t)G * GHW + x8 * 4] = pk;
        }
    } else {
        const int i = (blk - 512) * 256 + threadIdx.x;
        if (i < 576 * O_) {
            int o = i / 576, r = i % 576;
            int tap = r >> 6, c = r & 63;
            wtb[i] = f2bf(w[o * 576 + c * 9 + tap]);
        }
        if (i < 9 * 32 * 64) {
            int tap = i >> 11, m = (i >> 6) & 31, c = i & 63;
            owtb[i] = (m < M_) ? f2bf(ow[m * 576 + c * 9 + tap])
                               : (unsigned short)0;
        }
    }
}

// ---------------------------------------------------------------------------
// Fused deformable conv. Block = 64-px row segment, 4 waves.
// XCD banding (blockIdx%8 = XCD): XCD x owns rows [16x,16x+16) -> xT slice
// L2-resident per XCD (FETCH 197MB -> 5.5MB, rounds 4/6).
//
// LDS union 29.2 KB (offs folded after vals; extra barrier after A2's P reads)
// -> 5 blocks/CU (20 waves) vs round 6's 4.
//
// Phase A: stage P[3][66][72] (bf16, c-contig) from xT; MFMA offset conv.
// Phase B1: corner-PAIR sampling: per sample 2 b128 loads (row y0, row y1),
//   each = both x-corners x 4 ch; clamped-edge remap folded into pair weights
//   (cA/cB) -> values bit-identical to 4-corner form.
// Phase B2: 16x16x32 bf16 MFMA vs wtb (unchanged).
// ---------------------------------------------------------------------------
__global__ __launch_bounds__(256) void dcn_fused(
        const unsigned short* __restrict__ xT,
        const unsigned short* __restrict__ owtb, const float* __restrict__ ob,
        const unsigned short* __restrict__ wtb, const float* __restrict__ bias,
        float* __restrict__ out) {
    __shared__ union {
        unsigned short P[3][66][72];             // 28512 B (phase A)
        struct {
            unsigned short vals[64][192];        // 24576 B (phase B)
            float offs[M_ * 64];                 //  4608 B (after A2 barrier)
        } bv;                                    // 29184 B total
        float ep[4][16][65];                     // 16640 B (epilogue)
    } u;

    const int tid    = threadIdx.x;
    const int lane   = tid & 63;
    const int wslot  = __builtin_amdgcn_readfirstlane(tid >> 6);
    const int lane15 = lane & 15;
    const int quad   = lane >> 4;

    // XCD-banded remap (g%8 = XCD): XCD x -> rows [16x,16x+16), all b/half
    const int g    = blockIdx.x;
    const int xcd  = g & 7;
    const int slot = g >> 3;
    const int ho   = xcd * 16 + (slot >> 3);
    const int b    = (slot >> 1) & 3;
    const int wo_base = (slot & 1) << 6;

    const unsigned short* xT4b = xT + (size_t)b * 16 * GHW;

    // ---------------- Phase A1: stage 3 x-rows into P from xT ----------------
    // P[ky][r][c] = x[c][ho-1+ky][wo_base + r - 1],  r in [0,66)
    #pragma unroll
    for (int it = 0; it < 12; ++it) {
        const int t  = it * 4 + wslot;          // 0..47 = (ky, G)
        const int ky = t >> 4, G = t & 15;
        const int y  = ho - 1 + ky;
        const bool yv = (unsigned)y < (unsigned)H_;
        const int yc = min(max(y, 0), H_ - 1);
        const unsigned short* src = xT4b + ((size_t)G * HW_ + yc * W_) * 4;
        {
            const int r  = lane;
            const int cx = wo_base + r - 1;
            ushort4v p = {0, 0, 0, 0};
            if (yv && (unsigned)cx < (unsigned)W_)
                p = *(const ushort4v*)&src[cx * 4];
            *(ushort4v*)&u.P[ky][r][G * 4] = p;
        }
        if (lane < 2) {
            const int r  = 64 + lane;
            const int cx = wo_base + r - 1;
            ushort4v p = {0, 0, 0, 0};
            if (yv && (unsigned)cx < (unsigned)W_)
                p = *(const ushort4v*)&src[cx * 4];
            *(ushort4v*)&u.P[ky][r][G * 4] = p;
        }
    }
    __syncthreads();

    // ---------------- Phase A2: MFMA offset conv ----------------
    {
        floatx4 oa0 = (floatx4){0.f, 0.f, 0.f, 0.f};
        floatx4 oa1 = (floatx4){0.f, 0.f, 0.f, 0.f};
        const int pxt = wslot;
        #pragma unroll
        for (int ky = 0; ky < 3; ++ky) {
            #pragma unroll
            for (int kx = 0; kx < 3; ++kx) {
                const int tap = ky * 3 + kx;
                #pragma unroll
                for (int ks = 0; ks < 2; ++ks) {
                    const int kk = ks * 32 + quad * 8;
                    const short8 af =
                        *(const short8*)&u.P[ky][pxt * 16 + lane15 + kx][kk];
                    const short8 bf0 =
                        *(const short8*)&owtb[(size_t)(tap * 32 + lane15) * 64 + kk];
                    const short8 bf1 =
                        *(const short8*)&owtb[(size_t)(tap * 32 + 16 + lane15) * 64 + kk];
                    oa0 = __builtin_amdgcn_mfma_f32_16x16x32_bf16(af, bf0, oa0, 0, 0, 0);
                    oa1 = __builtin_amdgcn_mfma_f32_16x16x32_bf16(af, bf1, oa1, 0, 0, 0);
                }
            }
        }
        __syncthreads();   // all P reads done before offs (aliases P tail)
        *(floatx4*)&u.bv.offs[lane15 * 64 + pxt * 16 + quad * 4] = oa0;
        if (lane15 < 2)
            *(floatx4*)&u.bv.offs[(16 + lane15) * 64 + pxt * 16 + quad * 4] = oa1;
    }
    __syncthreads();

    // ---------------- Phase B: pair-sample (bf16->LDS) + MFMA MAC ----------------
    const int obase = wslot * 16;
    const int cg    = lane & 3;        // 4-channel sub-group within wave's 16 ch
    const int px16  = lane >> 2;       // pixel within px-tile
    floatx4 acc[4];
    #pragma unroll
    for (int t = 0; t < 4; ++t) acc[t] = (floatx4){0.f, 0.f, 0.f, 0.f};
    // wave's channels c = wslot*16 + cg*4 + q  ->  G-plane = wslot*4 + cg
    const unsigned short* xTw = xT4b + (size_t)(wslot * 4 + cg) * GHW;

    for (int chunk = 0; chunk < 3; ++chunk) {
        // --- B1: sampling. 3 taps x 4 px-tiles; 2 pair b128 loads each ---
        #pragma unroll
        for (int tl = 0; tl < 3; ++tl) {
            const int k  = chunk * 3 + tl;         // global tap 0..8
            const int ky = k / 3, kx = k % 3;
            const float oby = ob[2 * k], obx = ob[2 * k + 1];   // scalar loads
            #pragma unroll
            for (int pxt = 0; pxt < 4; ++pxt) {
                const int px = pxt * 16 + px16;
                const float offy = u.bv.offs[(2 * k)     * 64 + px] + oby;
                const float offx = u.bv.offs[(2 * k + 1) * 64 + px] + obx;
                const float py  = (float)(ho - 1 + ky) + offy;
                const float pxx = (float)(wo_base - 1 + kx + px) + offx;
                const float fy = floorf(py), fx = floorf(pxx);
                const int y0 = (int)fy, x0 = (int)fx;
                const int y1 = y0 + 1,  x1 = x0 + 1;
                const float wy1 = py - fy,  wy0 = 1.f - wy1;
                const float wx1 = pxx - fx, wx0 = 1.f - wx1;
                const bool y0v = (unsigned)y0 < (unsigned)H_;
                const bool y1v = (unsigned)y1 < (unsigned)H_;
                const bool x0v = (unsigned)x0 < (unsigned)W_;
                const bool x1v = (unsigned)x1 < (unsigned)W_;
                const float w00 = (y0v && x0v) ? wy0 * wx0 : 0.f;
                const float w01 = (y0v && x1v) ? wy0 * wx1 : 0.f;
                const float w10 = (y1v && x0v) ? wy1 * wx0 : 0.f;
                const float w11 = (y1v && x1v) ? wy1 * wx1 : 0.f;
                // pair base: both x-corners live at [bx, bx+1]
                const int bx  = min(max(x0, 0), W_ - 2);
                const int ry0 = min(max(y0, 0), H_ - 1);
                const int ry1 = min(max(y1, 0), H_ - 1);
                // remap corner weights onto the pair slots (exact at edges:
                // invalid corners carry zero weight)
                const float cA0 = (x0 == bx) ? w00 : ((x1 == bx) ? w01 : 0.f);
                const float cB0 = (x1 == bx + 1) ? w01 : ((x0 == bx + 1) ? w00 : 0.f);
                const float cA1 = (x0 == bx) ? w10 : ((x1 == bx) ? w11 : 0.f);
                const float cB1 = (x1 == bx + 1) ? w11 : ((x0 == bx + 1) ? w10 : 0.f);
                const ushort8v p0 = *(const ushort8v*)&xTw[(ry0 * W_ + bx) * 4];
                const ushort8v p1 = *(const ushort8v*)&xTw[(ry1 * W_ + bx) * 4];
                ushort4v pk;
                #pragma unroll
                for (int q = 0; q < 4; ++q) {
                    const float val = bf2f(p0[q])     * cA0 + bf2f(p0[4 + q]) * cB0
                                    + bf2f(p1[q])     * cA1 + bf2f(p1[4 + q]) * cB1;
                    pk[q] = f2bf(val);
                }
                // k_local = tl*64 + wslot*16 + cg*4 ; 16-B chunk low-3 bits
                // XOR-swizzled by px&7 (matches B2 read swizzle)
                const int cidx =
                    tl * 8 + (((wslot << 1) + (cg >> 1)) ^ (px & 7));
                *(ushort4v*)&u.bv.vals[px][cidx * 8 + (cg & 1) * 4] = pk;
            }
        }
        __syncthreads();

        // --- B2: MFMA MAC. 6 k-steps x 4 px-tiles ---
        const unsigned short* wrow =
            wtb + (size_t)(obase + lane15) * 576 + chunk * 192;
        #pragma unroll
        for (int ks = 0; ks < 6; ++ks) {
            const int kk = ks * 32 + quad * 8;
            const short8 bfrag = *(const short8*)(wrow + kk);
            const int ca  = (ks * 4 + quad) >> 3;                    // chunk group
            const int cbr = ((ks * 4 + quad) & 7) ^ (lane15 & 7);    // swizzled
            #pragma unroll
            for (int t = 0; t < 4; ++t) {
                const int row = t * 16 + lane15;
                const short8 afrag =
                    *(const short8*)&u.bv.vals[row][(ca * 8 + cbr) * 8];
                acc[t] = __builtin_amdgcn_mfma_f32_16x16x32_bf16(
                             afrag, bfrag, acc[t], 0, 0, 0);
            }
        }
        __syncthreads();
    }

    // ---------------- Epilogue: stage via LDS, coalesced store ----------------
    #pragma unroll
    for (int t = 0; t < 4; ++t)
        #pragma unroll
        for (int r = 0; r < 4; ++r)
            u.ep[wslot][lane15][t * 16 + quad * 4 + r] = acc[t][r];
    __syncthreads();
    #pragma unroll
    for (int oi = 0; oi < 16; ++oi) {
        const int o = obase + oi;
        out[(size_t)(b * O_ + o) * HW_ + ho * W_ + wo_base + lane] =
            u.ep[wslot][oi][lane] + bias[o];
    }
}

// ---------------------------------------------------------------------------
extern "C" void kernel_launch(void* const* d_in, const int* in_sizes, int n_in,
                              void* d_out, int out_size, void* d_ws, size_t ws_size,
                              hipStream_t stream) {
    const float* x    = (const float*)d_in[0];  // [4,64,128,128]
    const float* ow   = (const float*)d_in[1];  // [18,64,3,3]
    const float* ob   = (const float*)d_in[2];  // [18]
    const float* w    = (const float*)d_in[3];  // [64,64,3,3]
    const float* bias = (const float*)d_in[4];  // [64]
    float* out = (float*)d_out;                 // [4,64,128,128]

    unsigned short* wtb  = (unsigned short*)d_ws;       // [64][576]    73728 B
    unsigned short* owtb = wtb + 576 * O_;              // [9][32][64]  36864 B
    unsigned short* xT   = owtb + 9 * 32 * 64;          // [4][16][HW][4] 8.39 MB

    prep<<<512 + 144, 256, 0, stream>>>(x, w, ow, xT, wtb, owtb);
    dcn_fused<<<B_ * H_ * (W_ / 64), 256, 0, stream>>>(xT, owtb, ob, wtb, bias, out);
}

// Round 8
// 117.880 us; speedup vs baseline: 1.2114x; 1.2114x over previous
//
#include <hip/hip_runtime.h>

// Problem constants (B=4, C=64, H=W=128, O=64, K=3, stride=1, pad=1, dil=1)
#define B_   4
#define C_   64
#define O_   64
#define H_   128
#define W_   128
#define HW_  (H_ * W_)
#define KK_  9
#define M_   18          // 2*KK offset channels

typedef short  short8  __attribute__((ext_vector_type(8)));
typedef float  floatx4 __attribute__((ext_vector_type(4)));
typedef unsigned short ushort4v __attribute__((ext_vector_type(4)));
typedef unsigned short ushort8v __attribute__((ext_vector_type(8)));

static __device__ __forceinline__ unsigned short f2bf(float f) {
    unsigned int u = __float_as_uint(f);
    u += 0x7FFFu + ((u >> 16) & 1u);     // round-to-nearest-even
    return (unsigned short)(u >> 16);
}
static __device__ __forceinline__ float bf2f(unsigned short s) {
    return __uint_as_float((unsigned int)s << 16);
}

// ---------------------------------------------------------------------------
// Prep (single launch):
//  blocks [0,512):   x -> xT[b][g16][y][x][c16] bf16 (round-6 c16 layout:
//                    one corner x 4 ch = aligned 8 B, wave stays in ONE plane)
//  blocks [512,530): wtbf  = main-conv B-fragments in lane order
//                    [chunk*6+ks][otile][lane][8]  -> 1 KB contiguous per load
//  blocks [530,539): owtbf = offset-conv B-fragments in lane order
//                    [tap*2+ks][mtile][lane][8]
// ---------------------------------------------------------------------------
__global__ __launch_bounds__(256) void prep(
        const float* __restrict__ x, const float* __restrict__ w,
        const float* __restrict__ ow, unsigned short* __restrict__ xT,
        unsigned short* __restrict__ wtbf, unsigned short* __restrict__ owtbf) {
    const int blk = blockIdx.x;
    if (blk < 512) {
        __shared__ unsigned short T[128][72];   // [x][c], row padded to 72
        const int tid = threadIdx.x;
        const int y = blk & (H_ - 1);
        const int b = blk >> 7;
        const float* xby = x + (size_t)b * C_ * HW_ + y * W_;
        for (int i = tid; i < C_ * W_; i += 256) {
            const int c = i >> 7, xc = i & 127;
            T[xc][c] = f2bf(xby[(size_t)c * HW_ + xc]);
        }
        __syncthreads();
        unsigned short* dst = xT + (size_t)b * (4 * HW_ * 16) + y * (W_ * 16);
        for (int j = tid; j < 2048; j += 256) {
            const int g  = j >> 9;
            const int x8 = (j >> 2) & 127;
            const int c0 = (j & 3) * 4;
            const ushort4v pk = *(const ushort4v*)&T[x8][g * 16 + c0];
            *(ushort4v*)&dst[(size_t)g * (HW_ * 16) + x8 * 16 + c0] = pk;
        }
    } else if (blk < 530) {
        // wtbf: i in [0,4608) frags; i = (cks*4 + ot)*64 + lane
        const int i = (blk - 512) * 256 + threadIdx.x;
        const int lane = i & 63, rest = i >> 6;
        const int ot = rest & 3, cks = rest >> 2;      // cks = chunk*6+ks
        const int chunk = cks / 6, ks = cks % 6;
        const int o = ot * 16 + (lane & 15);
        const int kbase = chunk * 192 + ks * 32 + (lane >> 4) * 8;
        ushort8v pk;
        #pragma unroll
        for (int j = 0; j < 8; ++j) {
            const int k = kbase + j;                   // k = tap*64 + c
            pk[j] = f2bf(w[o * 576 + (k & 63) * 9 + (k >> 6)]);
        }
        *(ushort8v*)&wtbf[(size_t)i * 8] = pk;
    } else {
        // owtbf: i in [0,2304) frags; i = ((tks)*2 + tile)*64 + lane
        const int i = (blk - 530) * 256 + threadIdx.x;
        const int lane = i & 63, rest = i >> 6;
        const int tile = rest & 1, tks = rest >> 1;    // tks = tap*2+ks
        const int tap = tks >> 1, ks = tks & 1;
        const int m = tile * 16 + (lane & 15);
        const int cb = ks * 32 + (lane >> 4) * 8;
        ushort8v pk;
        #pragma unroll
        for (int j = 0; j < 8; ++j)
            pk[j] = (m < M_) ? f2bf(ow[m * 576 + (cb + j) * 9 + tap])
                             : (unsigned short)0;
        *(ushort8v*)&owtbf[(size_t)i * 8] = pk;
    }
}

// ---------------------------------------------------------------------------
// Fused deformable conv. Block = 64-px row segment, 4 waves.
// XCD banding (blockIdx%8 = XCD): XCD x owns rows [16x,16x+16) -> xT slice
// L2-resident per XCD (FETCH 197MB -> 5.5MB, rounds 4/6).
// LDS 29.2 KB (offs folded behind vals, barrier after A2) -> 5 blocks/CU.
//
// Phase A: stage P[3][66][72] (bf16, c-contig) from xT; MFMA offset conv
//          with lane-ordered owtbf fragments (contiguous 1 KB loads, L1-hot
//          across waves).
// Phase B1: round-6 4-corner sampling: wave-uniform 16-ch plane, 4 x b64
//           corner loads per (tap, px-tile); fp32 bilinear -> bf16 vals
//           (XOR-swizzled).
// Phase B2: 16x16x32 bf16 MFMA; B-frag from lane-ordered wtbf (1 KB bursts).
// ---------------------------------------------------------------------------
__global__ __launch_bounds__(256, 5) void dcn_fused(
        const unsigned short* __restrict__ xT,
        const unsigned short* __restrict__ owtbf, const float* __restrict__ ob,
        const unsigned short* __restrict__ wtbf, const float* __restrict__ bias,
        float* __restrict__ out) {
    __shared__ union {
        unsigned short P[3][66][72];             // 28512 B (phase A)
        struct {
            unsigned short vals[64][192];        // 24576 B (phase B)
            float offs[M_ * 64];                 //  4608 B (after A2 barrier)
        } bv;                                    // 29184 B total
        float ep[4][16][65];                     // 16640 B (epilogue)
    } u;

    const int tid    = threadIdx.x;
    const int lane   = tid & 63;
    const int wslot  = __builtin_amdgcn_readfirstlane(tid >> 6);
    const int lane15 = lane & 15;
    const int quad   = lane >> 4;

    // XCD-banded remap (g%8 = XCD): XCD x -> rows [16x,16x+16), all b/half
    const int g    = blockIdx.x;
    const int xcd  = g & 7;
    const int slot = g >> 3;
    const int ho   = xcd * 16 + (slot >> 3);
    const int b    = (slot >> 1) & 3;
    const int wo_base = (slot & 1) << 6;

    const unsigned short* xTb = xT + (size_t)b * (4 * HW_ * 16);

    // ---------------- Phase A1: stage 3 x-rows into P from xT ----------------
    // P[ky][r][c] = x[c][ho-1+ky][wo_base + r - 1],  r in [0,66)
    #pragma unroll
    for (int it = 0; it < 3; ++it) {
        const int t  = it * 4 + wslot;         // 0..11 = (ky, channel-group)
        const int ky = t >> 2, cgp = t & 3;
        const int y  = ho - 1 + ky;
        const bool yv = (unsigned)y < (unsigned)H_;
        const unsigned short* src = xTb + (size_t)cgp * (HW_ * 16) + y * (W_ * 16);
        #pragma unroll
        for (int pass = 0; pass < 2; ++pass) {
            const int r = pass * 64 + lane;
            if (r < 66) {
                const int cx = wo_base + r - 1;
                ushort8v p0 = {0, 0, 0, 0, 0, 0, 0, 0};
                ushort8v p1 = {0, 0, 0, 0, 0, 0, 0, 0};
                if (yv && (unsigned)cx < (unsigned)W_) {
                    p0 = *(const ushort8v*)&src[cx * 16];
                    p1 = *(const ushort8v*)&src[cx * 16 + 8];
                }
                *(ushort8v*)&u.P[ky][r][cgp * 16]     = p0;
                *(ushort8v*)&u.P[ky][r][cgp * 16 + 8] = p1;
            }
        }
    }
    __syncthreads();

    // ---------------- Phase A2: MFMA offset conv ----------------
    {
        floatx4 oa0 = (floatx4){0.f, 0.f, 0.f, 0.f};
        floatx4 oa1 = (floatx4){0.f, 0.f, 0.f, 0.f};
        const int pxt = wslot;
        #pragma unroll
        for (int ky = 0; ky < 3; ++ky) {
            #pragma unroll
            for (int kx = 0; kx < 3; ++kx) {
                const int tap = ky * 3 + kx;
                #pragma unroll
                for (int ks = 0; ks < 2; ++ks) {
                    const int kk = ks * 32 + quad * 8;
                    const short8 af =
                        *(const short8*)&u.P[ky][pxt * 16 + lane15 + kx][kk];
                    const int fb = ((tap * 2 + ks) * 2) * 64 + lane;
                    const short8 bf0 = *(const short8*)&owtbf[(size_t)fb * 8];
                    const short8 bf1 =
                        *(const short8*)&owtbf[(size_t)(fb + 64) * 8];
                    oa0 = __builtin_amdgcn_mfma_f32_16x16x32_bf16(af, bf0, oa0, 0, 0, 0);
                    oa1 = __builtin_amdgcn_mfma_f32_16x16x32_bf16(af, bf1, oa1, 0, 0, 0);
                }
            }
        }
        __syncthreads();   // all P reads done before offs (aliases P tail)
        *(floatx4*)&u.bv.offs[lane15 * 64 + pxt * 16 + quad * 4] = oa0;
        if (lane15 < 2)
            *(floatx4*)&u.bv.offs[(16 + lane15) * 64 + pxt * 16 + quad * 4] = oa1;
    }
    __syncthreads();

    // ---------------- Phase B: sample (bf16->LDS) + MFMA MAC ----------------
    const int obase = wslot * 16;
    const int cg    = lane & 3;        // 4-channel sub-group within wave's 16 ch
    const int px16  = lane >> 2;       // pixel within px-tile
    floatx4 acc[4];
    #pragma unroll
    for (int t = 0; t < 4; ++t) acc[t] = (floatx4){0.f, 0.f, 0.f, 0.f};
    // wave w samples channels [16w,16w+16): channel group g = wslot in xT
    const unsigned short* xTw = xTb + (size_t)wslot * (HW_ * 16);

    for (int chunk = 0; chunk < 3; ++chunk) {
        // --- B1: sampling. 3 taps x 4 px-tiles; 4 corner b64 loads each ---
        #pragma unroll
        for (int tl = 0; tl < 3; ++tl) {
            const int k  = chunk * 3 + tl;         // global tap 0..8
            const int ky = k / 3, kx = k % 3;
            const float oby = ob[2 * k], obx = ob[2 * k + 1];   // scalar loads
            #pragma unroll
            for (int pxt = 0; pxt < 4; ++pxt) {
                const int px = pxt * 16 + px16;
                const float offy = u.bv.offs[(2 * k)     * 64 + px] + oby;
                const float offx = u.bv.offs[(2 * k + 1) * 64 + px] + obx;
                const float py  = (float)(ho - 1 + ky) + offy;
                const float pxx = (float)(wo_base - 1 + kx + px) + offx;
                const float fy = floorf(py), fx = floorf(pxx);
                const int y0 = (int)fy, x0 = (int)fx;
                const int y1 = y0 + 1,  x1 = x0 + 1;
                const float wy1 = py - fy,  wy0 = 1.f - wy1;
                const float wx1 = pxx - fx, wx0 = 1.f - wx1;
                const bool y0v = (unsigned)y0 < (unsigned)H_;
                const bool y1v = (unsigned)y1 < (unsigned)H_;
                const bool x0v = (unsigned)x0 < (unsigned)W_;
                const bool x1v = (unsigned)x1 < (unsigned)W_;
                const float w00 = (y0v && x0v) ? wy0 * wx0 : 0.f;
                const float w01 = (y0v && x1v) ? wy0 * wx1 : 0.f;
                const float w10 = (y1v && x0v) ? wy1 * wx0 : 0.f;
                const float w11 = (y1v && x1v) ? wy1 * wx1 : 0.f;
                const int ry0 = min(max(y0, 0), H_ - 1);
                const int ry1 = min(max(y1, 0), H_ - 1);
                const int cx0 = min(max(x0, 0), W_ - 1);
                const int cx1 = min(max(x1, 0), W_ - 1);
                const int a00 = (ry0 * W_ + cx0) * 16 + cg * 4;
                const int a01 = (ry0 * W_ + cx1) * 16 + cg * 4;
                const int a10 = (ry1 * W_ + cx0) * 16 + cg * 4;
                const int a11 = (ry1 * W_ + cx1) * 16 + cg * 4;
                const ushort4v q00 = *(const ushort4v*)&xTw[a00];
                const ushort4v q01 = *(const ushort4v*)&xTw[a01];
                const ushort4v q10 = *(const ushort4v*)&xTw[a10];
                const ushort4v q11 = *(const ushort4v*)&xTw[a11];
                ushort4v pk;
                #pragma unroll
                for (int q = 0; q < 4; ++q) {
                    const float val = bf2f(q00[q]) * w00 + bf2f(q01[q]) * w01
                                    + bf2f(q10[q]) * w10 + bf2f(q11[q]) * w11;
                    pk[q] = f2bf(val);
                }
                // k_local = tl*64 + wslot*16 + cg*4 ; 16-B chunk low-3 bits
                // XOR-swizzled by px&7 (matches B2 read swizzle)
                const int cidx =
                    tl * 8 + (((wslot << 1) + (cg >> 1)) ^ (px & 7));
                *(ushort4v*)&u.bv.vals[px][cidx * 8 + (cg & 1) * 4] = pk;
            }
        }
        __syncthreads();

        // --- B2: MFMA MAC. 6 k-steps x 4 px-tiles ---
        #pragma unroll
        for (int ks = 0; ks < 6; ++ks) {
            const short8 bfrag = *(const short8*)
                &wtbf[(size_t)(((chunk * 6 + ks) * 4 + wslot) * 64 + lane) * 8];
            const int ca  = (ks * 4 + quad) >> 3;                    // chunk group
            const int cbr = ((ks * 4 + quad) & 7) ^ (lane15 & 7);    // swizzled
            #pragma unroll
            for (int t = 0; t < 4; ++t) {
                const int row = t * 16 + lane15;
                const short8 afrag =
                    *(const short8*)&u.bv.vals[row][(ca * 8 + cbr) * 8];
                acc[t] = __builtin_amdgcn_mfma_f32_16x16x32_bf16(
                             afrag, bfrag, acc[t], 0, 0, 0);
            }
        }
        __syncthreads();
    }

    // ---------------- Epilogue: stage via LDS, coalesced store ----------------
    #pragma unroll
    for (int t = 0; t < 4; ++t)
        #pragma unroll
        for (int r = 0; r < 4; ++r)
            u.ep[wslot][lane15][t * 16 + quad * 4 + r] = acc[t][r];
    __syncthreads();
    #pragma unroll
    for (int oi = 0; oi < 16; ++oi) {
        const int o = obase + oi;
        out[(size_t)(b * O_ + o) * HW_ + ho * W_ + wo_base + lane] =
            u.ep[wslot][oi][lane] + bias[o];
    }
}

// ---------------------------------------------------------------------------
extern "C" void kernel_launch(void* const* d_in, const int* in_sizes, int n_in,
                              void* d_out, int out_size, void* d_ws, size_t ws_size,
                              hipStream_t stream) {
    const float* x    = (const float*)d_in[0];  // [4,64,128,128]
    const float* ow   = (const float*)d_in[1];  // [18,64,3,3]
    const float* ob   = (const float*)d_in[2];  // [18]
    const float* w    = (const float*)d_in[3];  // [64,64,3,3]
    const float* bias = (const float*)d_in[4];  // [64]
    float* out = (float*)d_out;                 // [4,64,128,128]

    unsigned short* wtbf  = (unsigned short*)d_ws;      // 4608 frags  73728 B
    unsigned short* owtbf = wtbf + 4608 * 8;            // 2304 frags  36864 B
    unsigned short* xT    = owtbf + 2304 * 8;           // [4][4][HW][16] 8.39 MB

    prep<<<539, 256, 0, stream>>>(x, w, ow, xT, wtbf, owtbf);
    dcn_fused<<<B_ * H_ * (W_ / 64), 256, 0, stream>>>(xT, owtbf, ob, wtbf, bias, out);
}

// Round 9
// 115.468 us; speedup vs baseline: 1.2367x; 1.0209x over previous
//
#include <hip/hip_runtime.h>

// Problem constants (B=4, C=64, H=W=128, O=64, K=3, stride=1, pad=1, dil=1)
#define B_   4
#define C_   64
#define O_   64
#define H_   128
#define W_   128
#define HW_  (H_ * W_)
#define KK_  9
#define M_   18          // 2*KK offset channels

typedef short  short8  __attribute__((ext_vector_type(8)));
typedef float  floatx4 __attribute__((ext_vector_type(4)));
typedef unsigned short ushort4v __attribute__((ext_vector_type(4)));
typedef unsigned short ushort8v __attribute__((ext_vector_type(8)));

static __device__ __forceinline__ unsigned short f2bf(float f) {
    unsigned int u = __float_as_uint(f);
    u += 0x7FFFu + ((u >> 16) & 1u);     // round-to-nearest-even
    return (unsigned short)(u >> 16);
}
static __device__ __forceinline__ float bf2f(unsigned short s) {
    return __uint_as_float((unsigned int)s << 16);
}

// ---------------------------------------------------------------------------
// Prep (single launch) -- unchanged from round 8:
//  blocks [0,512):   x -> xT[b][g16][y][x][c16] bf16 (one corner x 4 ch = 8 B;
//                    a wave's 16-px b64 gather spans ~512 B -> TA sweet spot)
//  blocks [512,530): wtbf  = main-conv B-fragments in lane order
//                    [chunk*6+ks][otile][lane][8]  -> 1 KB contiguous per load
//  blocks [530,539): owtbf = offset-conv B-fragments in lane order
// ---------------------------------------------------------------------------
__global__ __launch_bounds__(256) void prep(
        const float* __restrict__ x, const float* __restrict__ w,
        const float* __restrict__ ow, unsigned short* __restrict__ xT,
        unsigned short* __restrict__ wtbf, unsigned short* __restrict__ owtbf) {
    const int blk = blockIdx.x;
    if (blk < 512) {
        __shared__ unsigned short T[128][72];   // [x][c], row padded to 72
        const int tid = threadIdx.x;
        const int y = blk & (H_ - 1);
        const int b = blk >> 7;
        const float* xby = x + (size_t)b * C_ * HW_ + y * W_;
        for (int i = tid; i < C_ * W_; i += 256) {
            const int c = i >> 7, xc = i & 127;
            T[xc][c] = f2bf(xby[(size_t)c * HW_ + xc]);
        }
        __syncthreads();
        unsigned short* dst = xT + (size_t)b * (4 * HW_ * 16) + y * (W_ * 16);
        for (int j = tid; j < 2048; j += 256) {
            const int g  = j >> 9;
            const int x8 = (j >> 2) & 127;
            const int c0 = (j & 3) * 4;
            const ushort4v pk = *(const ushort4v*)&T[x8][g * 16 + c0];
            *(ushort4v*)&dst[(size_t)g * (HW_ * 16) + x8 * 16 + c0] = pk;
        }
    } else if (blk < 530) {
        // wtbf: i = (cks*4 + ot)*64 + lane
        const int i = (blk - 512) * 256 + threadIdx.x;
        const int lane = i & 63, rest = i >> 6;
        const int ot = rest & 3, cks = rest >> 2;      // cks = chunk*6+ks
        const int chunk = cks / 6, ks = cks % 6;
        const int o = ot * 16 + (lane & 15);
        const int kbase = chunk * 192 + ks * 32 + (lane >> 4) * 8;
        ushort8v pk;
        #pragma unroll
        for (int j = 0; j < 8; ++j) {
            const int k = kbase + j;                   // k = tap*64 + c
            pk[j] = f2bf(w[o * 576 + (k & 63) * 9 + (k >> 6)]);
        }
        *(ushort8v*)&wtbf[(size_t)i * 8] = pk;
    } else {
        // owtbf: i = (tks*2 + tile)*64 + lane
        const int i = (blk - 530) * 256 + threadIdx.x;
        const int lane = i & 63, rest = i >> 6;
        const int tile = rest & 1, tks = rest >> 1;    // tks = tap*2+ks
        const int tap = tks >> 1, ks = tks & 1;
        const int m = tile * 16 + (lane & 15);
        const int cb = ks * 32 + (lane >> 4) * 8;
        ushort8v pk;
        #pragma unroll
        for (int j = 0; j < 8; ++j)
            pk[j] = (m < M_) ? f2bf(ow[m * 576 + (cb + j) * 9 + tap])
                             : (unsigned short)0;
        *(ushort8v*)&owtbf[(size_t)i * 8] = pk;
    }
}

// ---------------------------------------------------------------------------
// Fused deformable conv, wave-private phase B (barriers 9 -> 2).
// Block = 64-px row segment, 4 waves; wave w OWNS px tile [16w,16w+16):
//   A1: stage P[3][66][72] from xT (block-cooperative)          -> barrier
//   A2: wave computes its tile's 18 offsets via MFMA (regs)     -> barrier
//       (barrier because B1's vals writes alias P); then offs (+ob folded)
//       written to wave-private offs[w][18][16].
//   B (x3 chunks, NO barriers): B1 samples all 64 ch for own 16 px
//       (geometry once per tap, reused over 4 channel groups; 4-corner b64
//       loads, 512B/instr window); B2 MFMAs own vals rows against all 4
//       o-tiles (acc[4] over o). Wave-serial lgkmcnt ordering replaces
//       __syncthreads entirely.
//   Epilogue: acc -> wave-private scratch (own vals region) -> coalesced
//       stores. No barrier.
// XCD banding (blockIdx%8 = XCD): XCD x owns rows [16x,16x+16) -> xT slice
// L2-resident per XCD (FETCH 197MB -> ~7MB, rounds 4/6).
// ---------------------------------------------------------------------------
__global__ __launch_bounds__(256, 4) void dcn_fused(
        const unsigned short* __restrict__ xT,
        const unsigned short* __restrict__ owtbf, const float* __restrict__ ob,
        const unsigned short* __restrict__ wtbf, const float* __restrict__ bias,
        float* __restrict__ out) {
    __shared__ union {
        unsigned short P[3][66][72];             // 28512 B (phase A)
        struct {
            unsigned short vals[64][192];        // 24576 B (wave w: rows 16w..)
            float offs[4][M_][16];               //  4608 B (wave-private)
        } bv;                                    // 29184 B total
    } u;

    const int tid    = threadIdx.x;
    const int lane   = tid & 63;
    const int wslot  = __builtin_amdgcn_readfirstlane(tid >> 6);
    const int lane15 = lane & 15;
    const int quad   = lane >> 4;

    // XCD-banded remap (g%8 = XCD): XCD x -> rows [16x,16x+16), all b/half
    const int g    = blockIdx.x;
    const int xcd  = g & 7;
    const int slot = g >> 3;
    const int ho   = xcd * 16 + (slot >> 3);
    const int b    = (slot >> 1) & 3;
    const int wo_base = (slot & 1) << 6;

    const unsigned short* xTb = xT + (size_t)b * (4 * HW_ * 16);

    // ---------------- Phase A1: stage 3 x-rows into P from xT ----------------
    // P[ky][r][c] = x[c][ho-1+ky][wo_base + r - 1],  r in [0,66)
    #pragma unroll
    for (int it = 0; it < 3; ++it) {
        const int t  = it * 4 + wslot;         // 0..11 = (ky, channel-group)
        const int ky = t >> 2, cgp = t & 3;
        const int y  = ho - 1 + ky;
        const bool yv = (unsigned)y < (unsigned)H_;
        const unsigned short* src = xTb + (size_t)cgp * (HW_ * 16) + y * (W_ * 16);
        #pragma unroll
        for (int pass = 0; pass < 2; ++pass) {
            const int r = pass * 64 + lane;
            if (r < 66) {
                const int cx = wo_base + r - 1;
                ushort8v p0 = {0, 0, 0, 0, 0, 0, 0, 0};
                ushort8v p1 = {0, 0, 0, 0, 0, 0, 0, 0};
                if (yv && (unsigned)cx < (unsigned)W_) {
                    p0 = *(const ushort8v*)&src[cx * 16];
                    p1 = *(const ushort8v*)&src[cx * 16 + 8];
                }
                *(ushort8v*)&u.P[ky][r][cgp * 16]     = p0;
                *(ushort8v*)&u.P[ky][r][cgp * 16 + 8] = p1;
            }
        }
    }
    __syncthreads();

    // ---------------- Phase A2: MFMA offset conv (results in registers) -----
    floatx4 oa0 = (floatx4){0.f, 0.f, 0.f, 0.f};
    floatx4 oa1 = (floatx4){0.f, 0.f, 0.f, 0.f};
    {
        const int pxt = wslot;
        #pragma unroll
        for (int ky = 0; ky < 3; ++ky) {
            #pragma unroll
            for (int kx = 0; kx < 3; ++kx) {
                const int tap = ky * 3 + kx;
                #pragma unroll
                for (int ks = 0; ks < 2; ++ks) {
                    const int kk = ks * 32 + quad * 8;
                    const short8 af =
                        *(const short8*)&u.P[ky][pxt * 16 + lane15 + kx][kk];
                    const int fb = ((tap * 2 + ks) * 2) * 64 + lane;
                    const short8 bf0 = *(const short8*)&owtbf[(size_t)fb * 8];
                    const short8 bf1 =
                        *(const short8*)&owtbf[(size_t)(fb + 64) * 8];
                    oa0 = __builtin_amdgcn_mfma_f32_16x16x32_bf16(af, bf0, oa0, 0, 0, 0);
                    oa1 = __builtin_amdgcn_mfma_f32_16x16x32_bf16(af, bf1, oa1, 0, 0, 0);
                }
            }
        }
    }
    __syncthreads();   // all P reads done; vals/offs (aliasing P) now writable

    // Write wave-private offsets (+ offset-conv bias folded in).
    // D layout: m = lane15 (col), px16 = quad*4+r (row).
    {
        const float ob0 = ob[lane15];
        #pragma unroll
        for (int r = 0; r < 4; ++r) oa0[r] += ob0;
        *(floatx4*)&u.bv.offs[wslot][lane15][quad * 4] = oa0;
        if (lane15 < 2) {
            const float ob1 = ob[16 + lane15];
            #pragma unroll
            for (int r = 0; r < 4; ++r) oa1[r] += ob1;
            *(floatx4*)&u.bv.offs[wslot][16 + lane15][quad * 4] = oa1;
        }
    }

    // ---------------- Phase B: wave-private sample + MFMA (no barriers) -----
    const int cg4  = lane & 3;         // 4-channel sub-group
    const int px16 = lane >> 2;        // pixel within the wave's tile
    const int row  = wslot * 16 + px16;       // vals row owned by this lane
    floatx4 acc[4];                           // o-tiles 0..3
    #pragma unroll
    for (int t = 0; t < 4; ++t) acc[t] = (floatx4){0.f, 0.f, 0.f, 0.f};

    for (int chunk = 0; chunk < 3; ++chunk) {
        // --- B1: 3 taps x (geometry once -> 4 channel-group iterations) ---
        #pragma unroll
        for (int tl = 0; tl < 3; ++tl) {
            const int k  = chunk * 3 + tl;     // global tap 0..8
            const int ky = k / 3, kx = k % 3;
            const float offy = u.bv.offs[wslot][2 * k][px16];
            const float offx = u.bv.offs[wslot][2 * k + 1][px16];
            const float py  = (float)(ho - 1 + ky) + offy;
            const float pxx = (float)(wo_base - 1 + kx + wslot * 16 + px16) + offx;
            const float fy = floorf(py), fx = floorf(pxx);
            const int y0 = (int)fy, x0 = (int)fx;
            const int y1 = y0 + 1,  x1 = x0 + 1;
            const float wy1 = py - fy,  wy0 = 1.f - wy1;
            const float wx1 = pxx - fx, wx0 = 1.f - wx1;
            const bool y0v = (unsigned)y0 < (unsigned)H_;
            const bool y1v = (unsigned)y1 < (unsigned)H_;
            const bool x0v = (unsigned)x0 < (unsigned)W_;
            const bool x1v = (unsigned)x1 < (unsigned)W_;
            const float w00 = (y0v && x0v) ? wy0 * wx0 : 0.f;
            const float w01 = (y0v && x1v) ? wy0 * wx1 : 0.f;
            const float w10 = (y1v && x0v) ? wy1 * wx0 : 0.f;
            const float w11 = (y1v && x1v) ? wy1 * wx1 : 0.f;
            const int ry0 = min(max(y0, 0), H_ - 1);
            const int ry1 = min(max(y1, 0), H_ - 1);
            const int cx0 = min(max(x0, 0), W_ - 1);
            const int cx1 = min(max(x1, 0), W_ - 1);
            const int b00 = (ry0 * W_ + cx0) * 16 + cg4 * 4;
            const int b01 = (ry0 * W_ + cx1) * 16 + cg4 * 4;
            const int b10 = (ry1 * W_ + cx0) * 16 + cg4 * 4;
            const int b11 = (ry1 * W_ + cx1) * 16 + cg4 * 4;
            #pragma unroll
            for (int cgrp = 0; cgrp < 4; ++cgrp) {
                const unsigned short* xp = xTb + (size_t)cgrp * (HW_ * 16);
                const ushort4v q00 = *(const ushort4v*)&xp[b00];
                const ushort4v q01 = *(const ushort4v*)&xp[b01];
                const ushort4v q10 = *(const ushort4v*)&xp[b10];
                const ushort4v q11 = *(const ushort4v*)&xp[b11];
                ushort4v pk;
                #pragma unroll
                for (int q = 0; q < 4; ++q) {
                    const float val = bf2f(q00[q]) * w00 + bf2f(q01[q]) * w01
                                    + bf2f(q10[q]) * w10 + bf2f(q11[q]) * w11;
                    pk[q] = f2bf(val);
                }
                // 16B chunk (tl*8 + cgrp*2 + cg4>>1), low 3 bits ^ (row&7)
                const int cidx =
                    tl * 8 + (((cgrp << 1) + (cg4 >> 1)) ^ (px16 & 7));
                *(ushort4v*)&u.bv.vals[row][cidx * 8 + (cg4 & 1) * 4] = pk;
            }
        }

        // --- B2: MFMA own rows vs all 4 o-tiles (wave-private, no barrier) --
        #pragma unroll
        for (int ks = 0; ks < 6; ++ks) {
            const int c16 = ks * 4 + quad;
            const int ca  = c16 >> 3;
            const int cbr = (c16 & 7) ^ (lane15 & 7);
            const short8 afrag = *(const short8*)
                &u.bv.vals[wslot * 16 + lane15][(ca * 8 + cbr) * 8];
            #pragma unroll
            for (int t = 0; t < 4; ++t) {
                const short8 bfrag = *(const short8*)
                    &wtbf[(size_t)(((chunk * 6 + ks) * 4 + t) * 64 + lane) * 8];
                acc[t] = __builtin_amdgcn_mfma_f32_16x16x32_bf16(
                             afrag, bfrag, acc[t], 0, 0, 0);
            }
        }
    }

    // ---------------- Epilogue: wave-private staging, coalesced store -------
    // acc[t]: o = t*16+lane15 (col), px16 = quad*4+r (row). Stage [64 o][17]
    // floats inside the wave's own vals region (6144 B >= 4352 B needed).
    float* epw = (float*)&u.bv.vals[wslot * 16][0];
    #pragma unroll
    for (int t = 0; t < 4; ++t)
        #pragma unroll
        for (int r = 0; r < 4; ++r)
            epw[(t * 16 + lane15) * 17 + quad * 4 + r] = acc[t][r];

    const int wo = wo_base + wslot * 16 + lane15;
    #pragma unroll
    for (int i = 0; i < 16; ++i) {
        const int o = i * 4 + quad;
        out[(size_t)(b * O_ + o) * HW_ + ho * W_ + wo] =
            epw[o * 17 + lane15] + bias[o];
    }
}

// ---------------------------------------------------------------------------
extern "C" void kernel_launch(void* const* d_in, const int* in_sizes, int n_in,
                              void* d_out, int out_size, void* d_ws, size_t ws_size,
                              hipStream_t stream) {
    const float* x    = (const float*)d_in[0];  // [4,64,128,128]
    const float* ow   = (const float*)d_in[1];  // [18,64,3,3]
    const float* ob   = (const float*)d_in[2];  // [18]
    const float* w    = (const float*)d_in[3];  // [64,64,3,3]
    const float* bias = (const float*)d_in[4];  // [64]
    float* out = (float*)d_out;                 // [4,64,128,128]

    unsigned short* wtbf  = (unsigned short*)d_ws;      // 4608 frags  73728 B
    unsigned short* owtbf = wtbf + 4608 * 8;            // 2304 frags  36864 B
    unsigned short* xT    = owtbf + 2304 * 8;           // [4][4][HW][16] 8.39 MB

    prep<<<539, 256, 0, stream>>>(x, w, ow, xT, wtbf, owtbf);
    dcn_fused<<<B_ * H_ * (W_ / 64), 256, 0, stream>>>(xT, owtbf, ob, wtbf, bias, out);
}